// Round 15
// baseline (31.891 us; speedup 1.0000x reference)
//
#include <hip/hip_runtime.h>

#pragma clang fp contract(off)

#define HH 512
#define WW 640
#define HW (HH * WW)
#define NV4 (HW / 4)            // 81920 float4 per image
#define NITER 5                 // 5 float4 per thread = 20 pixels
#define V4_PER_ITER (NV4 / NITER)   // 16384 = 64 blocks * 256 threads
// grid (64, 32) = 2048 blocks = 256 CU x 8 blocks/CU -> single round, no tail

// Emulate PyPI-numpy (OpenBLAS, AVX2/FMA dispatch) float32 semantics.
// Identical op/rounding sequence to the VERIFIED (absmax 0.0, R5-R14)
// precompute: branchless scalar-select pivoting (permutation == swap, exact),
// reciprocal-diagonal trsm, FMA gemm chains. DO NOT alter any rounding in the
// chain through n0,n1,n2,depth2 (cancellation in depth2 is pole-amplified).
// POST-depth2 ops are only relative-error-sensitive: 1/depth2 then multiply
// is safe (<=1.5ulp rel ~ 0.1 abs at worst pole vs threshold 1.3e5).
__device__ __forceinline__ void precompute_static(
    const float* __restrict__ K9, const float* __restrict__ R9,
    const float* __restrict__ t3,
    float& M00, float& M01, float& M02,
    float& M10, float& M11, float& M12,
    float& M20, float& M21, float& M22,
    float& W0,  float& W1,  float& W2)
{
#pragma clang fp contract(off)
    const float K00=K9[0],K01=K9[1],K02=K9[2];
    const float K10=K9[3],K11=K9[4],K12=K9[5];
    const float K20=K9[6],K21=K9[7],K22=K9[8];
    const float R00=R9[0],R01=R9[1],R02=R9[2];
    const float R10=R9[3],R11=R9[4],R12=R9[5];
    const float R20=R9[6],R21=R9[7],R22=R9[8];
    const float t0=t3[0], t1=t3[1], t2=t3[2];

    float A00=K00,A01=K01,A02=K02;
    float A10=K10,A11=K11,A12=K12;
    float A20=K20,A21=K21,A22=K22;

    // ---- sgetf2 stage 0: pivot rows 0..2 on col 0 (first-max-wins) ----
    const float a0=__builtin_fabsf(A00), a1=__builtin_fabsf(A10), a2=__builtin_fabsf(A20);
    int p = (a1 > a0) ? 1 : 0;
    const float apv = (a1 > a0) ? a1 : a0;
    p = (a2 > apv) ? 2 : p;
    {   // swap row0 <-> row p (selects == permutation, exact)
        const float o0=A00,o1=A01,o2=A02;
        A00 = (p==1)?A10:((p==2)?A20:A00);
        A01 = (p==1)?A11:((p==2)?A21:A01);
        A02 = (p==1)?A12:((p==2)?A22:A02);
        A10 = (p==1)?o0:A10;  A11=(p==1)?o1:A11;  A12=(p==1)?o2:A12;
        A20 = (p==2)?o0:A20;  A21=(p==2)?o1:A21;  A22=(p==2)?o2:A22;
    }
    const float invd0 = 1.0f / A00;            // sscal by reciprocal
    A10 = A10 * invd0;  A20 = A20 * invd0;
    A11 = __builtin_fmaf(-A10, A01, A11);      // sger FMA (k=1 col)
    A21 = __builtin_fmaf(-A20, A01, A21);
    A12 = __builtin_fmaf(-A10, A02, A12);      // (k=2 col)
    A22 = __builtin_fmaf(-A20, A02, A22);

    // ---- stage 1: pivot rows 1..2 on col 1 ----
    const float b1a=__builtin_fabsf(A11), b2a=__builtin_fabsf(A21);
    const int q = (b2a > b1a) ? 2 : 1;
    {
        const float o0=A10,o1=A11,o2=A12;
        A10=(q==2)?A20:A10;  A11=(q==2)?A21:A11;  A12=(q==2)?A22:A12;
        A20=(q==2)?o0:A20;   A21=(q==2)?o1:A21;   A22=(q==2)?o2:A22;
    }
    const float invd1 = 1.0f / A11;
    A21 = A21 * invd1;
    A22 = __builtin_fmaf(-A21, A12, A22);
    const float invd2 = 1.0f / A22;

    // ---- sgetrs (B=I): laswp + unit-L solve + recip-diag U solve ----
    float Ki00,Ki01,Ki02,Ki10,Ki11,Ki12,Ki20,Ki21,Ki22;
#define SOLVE_COL(e0, e1, e2, KiA, KiB, KiC)                      \
    {                                                             \
        float b0=(e0), b1=(e1), b2=(e2);                          \
        float tt = b0;                                            \
        b0 = (p==1)?b1:((p==2)?b2:b0);                            \
        b1 = (p==1)?tt:b1;                                        \
        b2 = (p==2)?tt:b2;                                        \
        tt = b1;                                                  \
        b1 = (q==2)?b2:b1;                                        \
        b2 = (q==2)?tt:b2;                                        \
        b1 = __builtin_fmaf(-A10, b0, b1);                        \
        b2 = __builtin_fmaf(-A20, b0, b2);                        \
        b2 = __builtin_fmaf(-A21, b1, b2);                        \
        b2 = b2 * invd2;                                          \
        b0 = __builtin_fmaf(-A02, b2, b0);                        \
        b1 = __builtin_fmaf(-A12, b2, b1);                        \
        b1 = b1 * invd1;                                          \
        b0 = __builtin_fmaf(-A01, b1, b0);                        \
        b0 = b0 * invd0;                                          \
        KiA = b0; KiB = b1; KiC = b2;                             \
    }
    SOLVE_COL(1.0f, 0.0f, 0.0f, Ki00, Ki10, Ki20)
    SOLVE_COL(0.0f, 1.0f, 0.0f, Ki01, Ki11, Ki21)
    SOLVE_COL(0.0f, 0.0f, 1.0f, Ki02, Ki12, Ki22)
#undef SOLVE_COL

    // ---- T = K @ R^T (sgemm FMA chain, k ascending, from 0) ----
    float T00=0.0f,T01=0.0f,T02=0.0f,T10=0.0f,T11=0.0f,T12=0.0f,T20=0.0f,T21=0.0f,T22=0.0f;
    T00=__builtin_fmaf(K00,R00,T00); T00=__builtin_fmaf(K01,R01,T00); T00=__builtin_fmaf(K02,R02,T00);
    T01=__builtin_fmaf(K00,R10,T01); T01=__builtin_fmaf(K01,R11,T01); T01=__builtin_fmaf(K02,R12,T01);
    T02=__builtin_fmaf(K00,R20,T02); T02=__builtin_fmaf(K01,R21,T02); T02=__builtin_fmaf(K02,R22,T02);
    T10=__builtin_fmaf(K10,R00,T10); T10=__builtin_fmaf(K11,R01,T10); T10=__builtin_fmaf(K12,R02,T10);
    T11=__builtin_fmaf(K10,R10,T11); T11=__builtin_fmaf(K11,R11,T11); T11=__builtin_fmaf(K12,R12,T11);
    T12=__builtin_fmaf(K10,R20,T12); T12=__builtin_fmaf(K11,R21,T12); T12=__builtin_fmaf(K12,R22,T12);
    T20=__builtin_fmaf(K20,R00,T20); T20=__builtin_fmaf(K21,R01,T20); T20=__builtin_fmaf(K22,R02,T20);
    T21=__builtin_fmaf(K20,R10,T21); T21=__builtin_fmaf(K21,R11,T21); T21=__builtin_fmaf(K22,R12,T21);
    T22=__builtin_fmaf(K20,R20,T22); T22=__builtin_fmaf(K21,R21,T22); T22=__builtin_fmaf(K22,R22,T22);

    // ---- Wv = T @ (-t) ----
    const float n0=-t0, n1=-t1, n2=-t2;
    W0=0.0f; W0=__builtin_fmaf(T00,n0,W0); W0=__builtin_fmaf(T01,n1,W0); W0=__builtin_fmaf(T02,n2,W0);
    W1=0.0f; W1=__builtin_fmaf(T10,n0,W1); W1=__builtin_fmaf(T11,n1,W1); W1=__builtin_fmaf(T12,n2,W1);
    W2=0.0f; W2=__builtin_fmaf(T20,n0,W2); W2=__builtin_fmaf(T21,n1,W2); W2=__builtin_fmaf(T22,n2,W2);

    // ---- M = T @ Ki ----
    M00=0.0f; M00=__builtin_fmaf(T00,Ki00,M00); M00=__builtin_fmaf(T01,Ki10,M00); M00=__builtin_fmaf(T02,Ki20,M00);
    M01=0.0f; M01=__builtin_fmaf(T00,Ki01,M01); M01=__builtin_fmaf(T01,Ki11,M01); M01=__builtin_fmaf(T02,Ki21,M01);
    M02=0.0f; M02=__builtin_fmaf(T00,Ki02,M02); M02=__builtin_fmaf(T01,Ki12,M02); M02=__builtin_fmaf(T02,Ki22,M02);
    M10=0.0f; M10=__builtin_fmaf(T10,Ki00,M10); M10=__builtin_fmaf(T11,Ki10,M10); M10=__builtin_fmaf(T12,Ki20,M10);
    M11=0.0f; M11=__builtin_fmaf(T10,Ki01,M11); M11=__builtin_fmaf(T11,Ki11,M11); M11=__builtin_fmaf(T12,Ki21,M11);
    M12=0.0f; M12=__builtin_fmaf(T10,Ki02,M12); M12=__builtin_fmaf(T11,Ki12,M12); M12=__builtin_fmaf(T12,Ki22,M12);
    M20=0.0f; M20=__builtin_fmaf(T20,Ki00,M20); M20=__builtin_fmaf(T21,Ki10,M20); M20=__builtin_fmaf(T22,Ki20,M20);
    M21=0.0f; M21=__builtin_fmaf(T20,Ki01,M21); M21=__builtin_fmaf(T21,Ki11,M21); M21=__builtin_fmaf(T22,Ki21,M21);
    M22=0.0f; M22=__builtin_fmaf(T20,Ki02,M22); M22=__builtin_fmaf(T21,Ki12,M22); M22=__builtin_fmaf(T22,Ki22,M22);
}

__global__ __launch_bounds__(256, 8) void flow_fused_kernel(
    const float* __restrict__ dep, const float* __restrict__ msk,
    const float* __restrict__ tvec, const float* __restrict__ rot,
    const float* __restrict__ kmat, float* __restrict__ out)
{
#pragma clang fp contract(off)
    const int b = blockIdx.y;

    // wave-uniform precompute: operands scalar-load, all-register, branchless
    float M00,M01,M02,M10,M11,M12,M20,M21,M22,W0,W1,W2;
    precompute_static(kmat + b * 9, rot + b * 9, tvec + b * 3,
                      M00,M01,M02,M10,M11,M12,M20,M21,M22,W0,W1,W2);

    const int t = blockIdx.x * 256 + threadIdx.x;      // 0 .. 16383
    const int ibase = b * NV4;
    const int obase = b * (2 * NV4);

    // ---- 1-deep software pipeline: load k+1 before computing k ----
    float4 dv_cur = ((const float4*)dep)[ibase + t];
    float4 mv_cur = ((const float4*)msk)[ibase + t];
    float4 dv_nxt, mv_nxt;

    #pragma unroll
    for (int k = 0; k < NITER; ++k) {
        if (k + 1 < NITER) {
            const int i4n = t + (k + 1) * V4_PER_ITER;
            dv_nxt = ((const float4*)dep)[ibase + i4n];
            mv_nxt = ((const float4*)msk)[ibase + i4n];
        }
        __builtin_amdgcn_sched_barrier(0);   // pin: prefetch issued before compute

        const int i4  = t + k * V4_PER_ITER;
        const int pix = i4 * 4;
        const int y   = pix / WW;
        const int x0  = pix - y * WW;      // W % 4 == 0 -> row-uniform quad
        const float fy = (float)y;

        const float dvals[4] = {dv_cur.x, dv_cur.y, dv_cur.z, dv_cur.w};
        const float mvals[4] = {mv_cur.x, mv_cur.y, mv_cur.z, mv_cur.w};
        float uu[4], vv[4];

        #pragma unroll
        for (int j = 0; j < 4; ++j) {
            const float fx = (float)(x0 + j);
            // einsum AVX2 sop: acc = rnd(M0*x); acc = fma(M1,y,acc); acc += M2
            float i0 = M00 * fx; i0 = __builtin_fmaf(M01, fy, i0); i0 = i0 + M02;
            float i1 = M10 * fx; i1 = __builtin_fmaf(M11, fy, i1); i1 = i1 + M12;
            float i2 = M20 * fx; i2 = __builtin_fmaf(M21, fy, i2); i2 = i2 + M22;
            const float d_ = dvals[j];
            const float m_ = mvals[j];
            // num = Wv + d*inter : separate ufuncs (rounded mul, rounded add)
            const float p0 = d_ * i0;
            const float p1 = d_ * i1;
            const float p2 = d_ * i2;
            const float n0 = W0 + p0;
            const float n1 = W1 + p1;
            const float n2 = W2 + p2;
            const float om = 1.0f - m_;
            const float q0 = 1e30f * om;
            const float q1 = m_ * n2;
            const float depth2 = q0 + q1;          // bit-frozen through here
            // post-depth2: relative-error-only region (see header comment)
            const float r  = 1.0f / depth2;        // single IEEE divide
            const float u2 = n0 * r;
            const float v2 = n1 * r;
            uu[j] = (u2 - fx) * (1.0f / 640.0f);
            vv[j] = (v2 - fy) * (1.0f / 512.0f);   // exact: /2^9
        }

        ((float4*)out)[obase + i4]       = make_float4(uu[0], uu[1], uu[2], uu[3]);
        ((float4*)out)[obase + NV4 + i4] = make_float4(vv[0], vv[1], vv[2], vv[3]);

        if (k + 1 < NITER) { dv_cur = dv_nxt; mv_cur = mv_nxt; }
    }
}

extern "C" void kernel_launch(void* const* d_in, const int* in_sizes, int n_in,
                              void* d_out, int out_size, void* d_ws, size_t ws_size,
                              hipStream_t stream) {
    const float* dep = (const float*)d_in[0];
    const float* msk = (const float*)d_in[1];
    const float* tv  = (const float*)d_in[2];
    const float* rm  = (const float*)d_in[3];
    const float* km  = (const float*)d_in[4];
    float* out = (float*)d_out;

    dim3 grid(V4_PER_ITER / 256, 32);      // (64, 32) = 2048 blocks, zero tail
    flow_fused_kernel<<<grid, 256, 0, stream>>>(dep, msk, tv, rm, km, out);
}

// Round 16
// 30.439 us; speedup vs baseline: 1.0477x; 1.0477x over previous
//
#include <hip/hip_runtime.h>

#pragma clang fp contract(off)

#define HH 512
#define WW 640
#define HW (HH * WW)
#define NV4 (HW / 4)            // 81920 float4 per image
#define NITER 5                 // 5 float4 per thread = 20 pixels
#define V4_PER_ITER (NV4 / NITER)   // 16384 = 64 blocks * 256 threads
// grid (64, 32) = 2048 blocks = 256 CU x 8 blocks/CU -> single round, no tail
//
// FINAL (R16 = R14 config, best measured 30.63 us, absmax 0.0):
// memory-bound at ~95% of the practical floor (168 MB mandatory traffic
// / 6.3 TB/s + ~2 us launch). VALU (3 IEEE divides/pixel) verified OFF the
// critical path in R15 (VALUBusy 30->18% with zero time gain).

// Emulate PyPI-numpy (OpenBLAS, AVX2/FMA dispatch) float32 semantics.
// Identical op/rounding sequence to the VERIFIED (absmax 0.0, R5-R14)
// precompute: branchless scalar-select pivoting (permutation == swap, exact),
// reciprocal-diagonal trsm, FMA gemm chains. DO NOT alter any rounding.
__device__ __forceinline__ void precompute_static(
    const float* __restrict__ K9, const float* __restrict__ R9,
    const float* __restrict__ t3,
    float& M00, float& M01, float& M02,
    float& M10, float& M11, float& M12,
    float& M20, float& M21, float& M22,
    float& W0,  float& W1,  float& W2)
{
#pragma clang fp contract(off)
    const float K00=K9[0],K01=K9[1],K02=K9[2];
    const float K10=K9[3],K11=K9[4],K12=K9[5];
    const float K20=K9[6],K21=K9[7],K22=K9[8];
    const float R00=R9[0],R01=R9[1],R02=R9[2];
    const float R10=R9[3],R11=R9[4],R12=R9[5];
    const float R20=R9[6],R21=R9[7],R22=R9[8];
    const float t0=t3[0], t1=t3[1], t2=t3[2];

    float A00=K00,A01=K01,A02=K02;
    float A10=K10,A11=K11,A12=K12;
    float A20=K20,A21=K21,A22=K22;

    // ---- sgetf2 stage 0: pivot rows 0..2 on col 0 (first-max-wins) ----
    const float a0=__builtin_fabsf(A00), a1=__builtin_fabsf(A10), a2=__builtin_fabsf(A20);
    int p = (a1 > a0) ? 1 : 0;
    const float apv = (a1 > a0) ? a1 : a0;
    p = (a2 > apv) ? 2 : p;
    {   // swap row0 <-> row p (selects == permutation, exact)
        const float o0=A00,o1=A01,o2=A02;
        A00 = (p==1)?A10:((p==2)?A20:A00);
        A01 = (p==1)?A11:((p==2)?A21:A01);
        A02 = (p==1)?A12:((p==2)?A22:A02);
        A10 = (p==1)?o0:A10;  A11=(p==1)?o1:A11;  A12=(p==1)?o2:A12;
        A20 = (p==2)?o0:A20;  A21=(p==2)?o1:A21;  A22=(p==2)?o2:A22;
    }
    const float invd0 = 1.0f / A00;            // sscal by reciprocal
    A10 = A10 * invd0;  A20 = A20 * invd0;
    A11 = __builtin_fmaf(-A10, A01, A11);      // sger FMA (k=1 col)
    A21 = __builtin_fmaf(-A20, A01, A21);
    A12 = __builtin_fmaf(-A10, A02, A12);      // (k=2 col)
    A22 = __builtin_fmaf(-A20, A02, A22);

    // ---- stage 1: pivot rows 1..2 on col 1 ----
    const float b1a=__builtin_fabsf(A11), b2a=__builtin_fabsf(A21);
    const int q = (b2a > b1a) ? 2 : 1;
    {
        const float o0=A10,o1=A11,o2=A12;
        A10=(q==2)?A20:A10;  A11=(q==2)?A21:A11;  A12=(q==2)?A22:A12;
        A20=(q==2)?o0:A20;   A21=(q==2)?o1:A21;   A22=(q==2)?o2:A22;
    }
    const float invd1 = 1.0f / A11;
    A21 = A21 * invd1;
    A22 = __builtin_fmaf(-A21, A12, A22);
    const float invd2 = 1.0f / A22;

    // ---- sgetrs (B=I): laswp + unit-L solve + recip-diag U solve ----
    float Ki00,Ki01,Ki02,Ki10,Ki11,Ki12,Ki20,Ki21,Ki22;
#define SOLVE_COL(e0, e1, e2, KiA, KiB, KiC)                      \
    {                                                             \
        float b0=(e0), b1=(e1), b2=(e2);                          \
        float tt = b0;                                            \
        b0 = (p==1)?b1:((p==2)?b2:b0);                            \
        b1 = (p==1)?tt:b1;                                        \
        b2 = (p==2)?tt:b2;                                        \
        tt = b1;                                                  \
        b1 = (q==2)?b2:b1;                                        \
        b2 = (q==2)?tt:b2;                                        \
        b1 = __builtin_fmaf(-A10, b0, b1);                        \
        b2 = __builtin_fmaf(-A20, b0, b2);                        \
        b2 = __builtin_fmaf(-A21, b1, b2);                        \
        b2 = b2 * invd2;                                          \
        b0 = __builtin_fmaf(-A02, b2, b0);                        \
        b1 = __builtin_fmaf(-A12, b2, b1);                        \
        b1 = b1 * invd1;                                          \
        b0 = __builtin_fmaf(-A01, b1, b0);                        \
        b0 = b0 * invd0;                                          \
        KiA = b0; KiB = b1; KiC = b2;                             \
    }
    SOLVE_COL(1.0f, 0.0f, 0.0f, Ki00, Ki10, Ki20)
    SOLVE_COL(0.0f, 1.0f, 0.0f, Ki01, Ki11, Ki21)
    SOLVE_COL(0.0f, 0.0f, 1.0f, Ki02, Ki12, Ki22)
#undef SOLVE_COL

    // ---- T = K @ R^T (sgemm FMA chain, k ascending, from 0) ----
    float T00=0.0f,T01=0.0f,T02=0.0f,T10=0.0f,T11=0.0f,T12=0.0f,T20=0.0f,T21=0.0f,T22=0.0f;
    T00=__builtin_fmaf(K00,R00,T00); T00=__builtin_fmaf(K01,R01,T00); T00=__builtin_fmaf(K02,R02,T00);
    T01=__builtin_fmaf(K00,R10,T01); T01=__builtin_fmaf(K01,R11,T01); T01=__builtin_fmaf(K02,R12,T01);
    T02=__builtin_fmaf(K00,R20,T02); T02=__builtin_fmaf(K01,R21,T02); T02=__builtin_fmaf(K02,R22,T02);
    T10=__builtin_fmaf(K10,R00,T10); T10=__builtin_fmaf(K11,R01,T10); T10=__builtin_fmaf(K12,R02,T10);
    T11=__builtin_fmaf(K10,R10,T11); T11=__builtin_fmaf(K11,R11,T11); T11=__builtin_fmaf(K12,R12,T11);
    T12=__builtin_fmaf(K10,R20,T12); T12=__builtin_fmaf(K11,R21,T12); T12=__builtin_fmaf(K12,R22,T12);
    T20=__builtin_fmaf(K20,R00,T20); T20=__builtin_fmaf(K21,R01,T20); T20=__builtin_fmaf(K22,R02,T20);
    T21=__builtin_fmaf(K20,R10,T21); T21=__builtin_fmaf(K21,R11,T21); T21=__builtin_fmaf(K22,R12,T21);
    T22=__builtin_fmaf(K20,R20,T22); T22=__builtin_fmaf(K21,R21,T22); T22=__builtin_fmaf(K22,R22,T22);

    // ---- Wv = T @ (-t) ----
    const float n0=-t0, n1=-t1, n2=-t2;
    W0=0.0f; W0=__builtin_fmaf(T00,n0,W0); W0=__builtin_fmaf(T01,n1,W0); W0=__builtin_fmaf(T02,n2,W0);
    W1=0.0f; W1=__builtin_fmaf(T10,n0,W1); W1=__builtin_fmaf(T11,n1,W1); W1=__builtin_fmaf(T12,n2,W1);
    W2=0.0f; W2=__builtin_fmaf(T20,n0,W2); W2=__builtin_fmaf(T21,n1,W2); W2=__builtin_fmaf(T22,n2,W2);

    // ---- M = T @ Ki ----
    M00=0.0f; M00=__builtin_fmaf(T00,Ki00,M00); M00=__builtin_fmaf(T01,Ki10,M00); M00=__builtin_fmaf(T02,Ki20,M00);
    M01=0.0f; M01=__builtin_fmaf(T00,Ki01,M01); M01=__builtin_fmaf(T01,Ki11,M01); M01=__builtin_fmaf(T02,Ki21,M01);
    M02=0.0f; M02=__builtin_fmaf(T00,Ki02,M02); M02=__builtin_fmaf(T01,Ki12,M02); M02=__builtin_fmaf(T02,Ki22,M02);
    M10=0.0f; M10=__builtin_fmaf(T10,Ki00,M10); M10=__builtin_fmaf(T11,Ki10,M10); M10=__builtin_fmaf(T12,Ki20,M10);
    M11=0.0f; M11=__builtin_fmaf(T10,Ki01,M11); M11=__builtin_fmaf(T11,Ki11,M11); M11=__builtin_fmaf(T12,Ki21,M11);
    M12=0.0f; M12=__builtin_fmaf(T10,Ki02,M12); M12=__builtin_fmaf(T11,Ki12,M12); M12=__builtin_fmaf(T12,Ki22,M12);
    M20=0.0f; M20=__builtin_fmaf(T20,Ki00,M20); M20=__builtin_fmaf(T21,Ki10,M20); M20=__builtin_fmaf(T22,Ki20,M20);
    M21=0.0f; M21=__builtin_fmaf(T20,Ki01,M21); M21=__builtin_fmaf(T21,Ki11,M21); M21=__builtin_fmaf(T22,Ki21,M21);
    M22=0.0f; M22=__builtin_fmaf(T20,Ki02,M22); M22=__builtin_fmaf(T21,Ki12,M22); M22=__builtin_fmaf(T22,Ki22,M22);
}

__global__ __launch_bounds__(256, 8) void flow_fused_kernel(
    const float* __restrict__ dep, const float* __restrict__ msk,
    const float* __restrict__ tvec, const float* __restrict__ rot,
    const float* __restrict__ kmat, float* __restrict__ out)
{
#pragma clang fp contract(off)
    const int b = blockIdx.y;

    // wave-uniform precompute: operands scalar-load, all-register, branchless
    float M00,M01,M02,M10,M11,M12,M20,M21,M22,W0,W1,W2;
    precompute_static(kmat + b * 9, rot + b * 9, tvec + b * 3,
                      M00,M01,M02,M10,M11,M12,M20,M21,M22,W0,W1,W2);

    const int t = blockIdx.x * 256 + threadIdx.x;      // 0 .. 16383
    const int ibase = b * NV4;
    const int obase = b * (2 * NV4);

    // ---- 1-deep software pipeline: load k+1 before computing k ----
    float4 dv_cur = ((const float4*)dep)[ibase + t];
    float4 mv_cur = ((const float4*)msk)[ibase + t];
    float4 dv_nxt, mv_nxt;

    #pragma unroll
    for (int k = 0; k < NITER; ++k) {
        if (k + 1 < NITER) {
            const int i4n = t + (k + 1) * V4_PER_ITER;
            dv_nxt = ((const float4*)dep)[ibase + i4n];
            mv_nxt = ((const float4*)msk)[ibase + i4n];
        }
        __builtin_amdgcn_sched_barrier(0);   // pin: prefetch issued before compute

        const int i4  = t + k * V4_PER_ITER;
        const int pix = i4 * 4;
        const int y   = pix / WW;
        const int x0  = pix - y * WW;      // W % 4 == 0 -> row-uniform quad
        const float fy = (float)y;

        const float dvals[4] = {dv_cur.x, dv_cur.y, dv_cur.z, dv_cur.w};
        const float mvals[4] = {mv_cur.x, mv_cur.y, mv_cur.z, mv_cur.w};
        float uu[4], vv[4];

        #pragma unroll
        for (int j = 0; j < 4; ++j) {
            const float fx = (float)(x0 + j);
            // einsum AVX2 sop: acc = rnd(M0*x); acc = fma(M1,y,acc); acc += M2
            float i0 = M00 * fx; i0 = __builtin_fmaf(M01, fy, i0); i0 = i0 + M02;
            float i1 = M10 * fx; i1 = __builtin_fmaf(M11, fy, i1); i1 = i1 + M12;
            float i2 = M20 * fx; i2 = __builtin_fmaf(M21, fy, i2); i2 = i2 + M22;
            const float d_ = dvals[j];
            const float m_ = mvals[j];
            // num = Wv + d*inter : separate ufuncs (rounded mul, rounded add)
            const float p0 = d_ * i0;
            const float p1 = d_ * i1;
            const float p2 = d_ * i2;
            const float n0 = W0 + p0;
            const float n1 = W1 + p1;
            const float n2 = W2 + p2;
            const float om = 1.0f - m_;
            const float q0 = 1e30f * om;
            const float q1 = m_ * n2;
            const float depth2 = q0 + q1;
            const float u2 = n0 / depth2;   // IEEE f32 div (pole-critical)
            const float v2 = n1 / depth2;
            uu[j] = (u2 - fx) / 640.0f;                 // true divide (640 = 5*2^7)
            vv[j] = (v2 - fy) * (1.0f / 512.0f);        // exact: /2^9 == *2^-9
        }

        ((float4*)out)[obase + i4]       = make_float4(uu[0], uu[1], uu[2], uu[3]);
        ((float4*)out)[obase + NV4 + i4] = make_float4(vv[0], vv[1], vv[2], vv[3]);

        if (k + 1 < NITER) { dv_cur = dv_nxt; mv_cur = mv_nxt; }
    }
}

extern "C" void kernel_launch(void* const* d_in, const int* in_sizes, int n_in,
                              void* d_out, int out_size, void* d_ws, size_t ws_size,
                              hipStream_t stream) {
    const float* dep = (const float*)d_in[0];
    const float* msk = (const float*)d_in[1];
    const float* tv  = (const float*)d_in[2];
    const float* rm  = (const float*)d_in[3];
    const float* km  = (const float*)d_in[4];
    float* out = (float*)d_out;

    dim3 grid(V4_PER_ITER / 256, 32);      // (64, 32) = 2048 blocks, zero tail
    flow_fused_kernel<<<grid, 256, 0, stream>>>(dep, msk, tv, rm, km, out);
}